// Round 7
// baseline (284.060 us; speedup 1.0000x reference)
//
#include <hip/hip_runtime.h>
#include <stdint.h>

// ============================================================================
// ExpertMLP: out = relu(x @ W_fc^T)^2 @ W_proj^T    (fp32 in/out, bf16 MFMA)
// R13: GEMM1 = gemm_h1 (R12, best measured 82.1 us) unchanged.
//      GEMM2 = gemm2_sk8: SPLIT-K=2 at 256x256 tile using R8's verified
//        4-phase/K-tile gemm8p loop (my best 256^2 structure). Grid
//        (4n,32m,2kz)=256 blocks=1/CU, each K-window 2048 (32 K-tiles).
//        Epilogue: fp32 atomicAdd (2 addends + zero init -> order-invariant);
//        out pre-zeroed with hipMemsetAsync (graph-capturable).
//      cvt_all unchanged.
// ws: h[64Mi] | x_bf[16Mi] | wfc_bf[8Mi] | wproj_bf[8Mi] = 96 MiB.
// ============================================================================

typedef __attribute__((ext_vector_type(8))) short bf16x8;   // 8 bf16 = 4 VGPRs
typedef __attribute__((ext_vector_type(4))) float f32x4;    // MFMA C/D

typedef const __attribute__((address_space(1))) unsigned int* gas_u32p;
typedef __attribute__((address_space(3))) unsigned int* las_u32p;

__device__ __forceinline__ void load16_to_lds(const void* gptr, void* lptr) {
    __builtin_amdgcn_global_load_lds((gas_u32p)gptr, (las_u32p)lptr, 16, 0, 0);
}

__device__ __forceinline__ void dsr128(bf16x8& d, unsigned off) {
    asm volatile("ds_read_b128 %0, %1" : "=v"(d) : "v"(off));
}

__device__ __forceinline__ unsigned short f2bf(float f) {
    unsigned int u = __float_as_uint(f);
    u += 0x7FFFu + ((u >> 16) & 1u);   // RNE; finite inputs
    return (unsigned short)(u >> 16);
}

#define LGKM(n) do { \
    asm volatile("s_waitcnt lgkmcnt(%0)" :: "i"(n) : "memory"); \
    __builtin_amdgcn_sched_barrier(0); } while (0)
#define VMC(n) do { \
    asm volatile("s_waitcnt vmcnt(%0)" :: "i"(n) : "memory"); \
    __builtin_amdgcn_sched_barrier(0); } while (0)
#define LGKM0_FENCE() LGKM(0)

// --------------------------------------------------------------------------
// Single fused fp32->bf16 prepass: x (2M float4) | W_fc (1M) | W_proj (1M).
// --------------------------------------------------------------------------
__global__ void cvt_all(const float4* __restrict__ x,  ushort4* __restrict__ xb,
                        const float4* __restrict__ wf, ushort4* __restrict__ wfb,
                        const float4* __restrict__ wp, ushort4* __restrict__ wpb)
{
    const int base = blockIdx.x * 1024 + threadIdx.x;
    #pragma unroll
    for (int j = 0; j < 4; j++) {
        const int i = base + j * 256;
        const float4* s; ushort4* d; int k;
        if (i < (1 << 21))            { s = x;  d = xb;  k = i; }
        else if (i < 3 * (1 << 20))   { s = wf; d = wfb; k = i - (1 << 21); }
        else                          { s = wp; d = wpb; k = i - 3 * (1 << 20); }
        float4 v = s[k];
        ushort4 o;
        o.x = f2bf(v.x); o.y = f2bf(v.y); o.z = f2bf(v.z); o.w = f2bf(v.w);
        d[k] = o;
    }
}

// --------------------------------------------------------------------------
// GEMM1: h = relu(A.B^T)^2, bf16 out. BM=128 BN=256 BK=32. (R12, verified)
// 512 thr, 8 waves 2Mx4N (wave 64x64). LDS: 3 bufs x 24KiB -> 2 blocks/CU.
// --------------------------------------------------------------------------
__global__ __launch_bounds__(512, 4)
void gemm_h1(const unsigned short* __restrict__ A,
             const unsigned short* __restrict__ B,
             unsigned short* __restrict__ C, int M, int N, int K)
{
    constexpr int ABYT = 8192;              // A region: 128r x 32k x 2B
    constexpr int BBYT = 16384;             // B region: 256r x 32k x 2B
    constexpr int BUFB = ABYT + BBYT;       // 24 KiB
    (void)M;

    __shared__ char lds[3 * BUFB];          // 72 KiB -> 2 blocks/CU

    const int tid  = threadIdx.x;
    const int lane = tid & 63;
    const int wave = tid >> 6;
    const int wm   = wave >> 2;             // 0..1 -> rows wm*64
    const int wn   = wave & 3;              // 0..3 -> cols wn*64
    const int quad = lane >> 4;
    const int m16  = lane & 15;

    const int gx = gridDim.x;               // 16
    int flat = blockIdx.y * gx + blockIdx.x;
    const int cpx = (gx * gridDim.y) >> 3;  // 128
    flat = (flat & 7) * cpx + (flat >> 3);
    const long bm0 = (long)(flat & 63) * 128;
    const long bn0 = (long)(flat >> 6) * 256;

    const int srow   = tid >> 2;
    const int schunk = (tid & 3) ^ ((tid >> 3) & 3);
    const unsigned short* gA = A + (bm0 + srow) * (long)K + schunk * 8;
    const unsigned short* gB = B + (bn0 + srow) * (long)K + schunk * 8;

    unsigned offA[4], offB[4];
    #pragma unroll
    for (int i = 0; i < 4; i++) {
        const unsigned lo = (unsigned)((wm * 64 + i * 16 + m16) * 64 + quad * 16);
        offA[i] = lo ^ (((lo >> 7) & 3) << 4);
    }
    #pragma unroll
    for (int j = 0; j < 4; j++) {
        const unsigned lo = (unsigned)((wn * 64 + j * 16 + m16) * 64 + quad * 16);
        offB[j] = ABYT + (lo ^ (((lo >> 7) & 3) << 4));
    }

    const unsigned base =
        (unsigned)(unsigned long long)(las_u32p)(void*)lds;

    f32x4 acc[4][4];
    #pragma unroll
    for (int i = 0; i < 4; i++)
        #pragma unroll
        for (int j = 0; j < 4; j++)
            acc[i][j] = (f32x4)0.0f;

    const int NT = K >> 5;   // BK=32 -> 32 tiles at K=1024

    #define STG(po_, t_) do { \
        char* _d = (char*)lds + (po_) + tid * 16; \
        load16_to_lds(gA + (long)(t_) * 32, _d); \
        const unsigned short* _sB = gB + (long)(t_) * 32; \
        load16_to_lds(_sB, _d + ABYT); \
        load16_to_lds(_sB + 128l * K, _d + ABYT + 8192); } while (0)

    STG(0, 0);
    if (NT > 1) {
        STG(BUFB, 1);
        VMC(3);
    } else {
        VMC(0);
    }
    __builtin_amdgcn_s_barrier();

    unsigned co = 0, no = BUFB, po = 2 * BUFB;

    for (int t = 0; t < NT; ++t) {
        bf16x8 a[4], b[4];

        #pragma unroll
        for (int j = 0; j < 4; j++) dsr128(b[j], base + co + offB[j]);
        #pragma unroll
        for (int i = 0; i < 4; i++) dsr128(a[i], base + co + offA[i]);

        if (t + 2 < NT) STG(po, t + 2);

        LGKM(2);
        __builtin_amdgcn_s_setprio(1);
        #pragma unroll
        for (int i = 0; i < 2; i++)
            #pragma unroll
            for (int j = 0; j < 4; j++)
                acc[i][j] = __builtin_amdgcn_mfma_f32_16x16x32_bf16(
                    a[i], b[j], acc[i][j], 0, 0, 0);
        __builtin_amdgcn_s_setprio(0);

        LGKM(0);
        __builtin_amdgcn_s_setprio(1);
        #pragma unroll
        for (int i = 2; i < 4; i++)
            #pragma unroll
            for (int j = 0; j < 4; j++)
                acc[i][j] = __builtin_amdgcn_mfma_f32_16x16x32_bf16(
                    a[i], b[j], acc[i][j], 0, 0, 0);
        __builtin_amdgcn_s_setprio(0);

        if (t + 2 < NT) VMC(3);
        else            VMC(0);
        __builtin_amdgcn_s_barrier();

        const unsigned tmp = po; po = co; co = no; no = tmp;
    }
    #undef STG

    const long baseRow = bm0 + wm * 64 + quad * 4;
    const long baseCol = bn0 + wn * 64 + m16;
    #pragma unroll
    for (int i = 0; i < 4; i++) {
        #pragma unroll
        for (int j = 0; j < 4; j++) {
            #pragma unroll
            for (int r = 0; r < 4; r++) {
                float v = acc[i][j][r];
                v = (v > 0.0f) ? v * v : 0.0f;
                const long row = baseRow + i * 16 + r;
                const long col = baseCol + j * 16;
                C[row * (long)N + col] = f2bf(v);
            }
        }
    }
}

// --------------------------------------------------------------------------
// GEMM2: out += A.B^T over K-window [kz*2048,(kz+1)*2048), fp32 atomicAdd.
// 256x256 tile, BK=64, 512 thr, 8 waves 2Mx4N (wave 128x64).
// R8's verified 4-phase K-loop (gemm8p<NF=4>), KEEP=6 counted vmcnt.
// Grid (4,32,2) = 256 blocks = 1/CU, single pass. out MUST be pre-zeroed.
// Exactly 2 addends per element + zero-init -> fp32 add order-invariant.
// --------------------------------------------------------------------------
__global__ __launch_bounds__(512, 2)
void gemm2_sk8(const unsigned short* __restrict__ A,
               const unsigned short* __restrict__ B,
               float* __restrict__ C, int M, int N, int K)
{
    constexpr int AKH  = 16384;             // A kh-region: 256r x 32k x 2B
    constexpr int BKH  = 16384;             // B kh-region: 256r x 32k x 2B
    constexpr int BOFF = 2 * AKH;
    constexpr int BUFB = 2 * AKH + 2 * BKH; // 64 KiB
    constexpr int KEEP = 6;
    constexpr int KW   = 2048;              // per-block K window
    (void)M;

    __shared__ char lds[2 * BUFB];          // 128 KiB

    const int tid  = threadIdx.x;
    const int lane = tid & 63;
    const int wave = tid >> 6;
    const int wm   = wave >> 2;             // 0..1 -> rows wm*128
    const int wn   = wave & 3;              // 0..3 -> cols wn*64
    const int quad = lane >> 4;
    const int m16  = lane & 15;

    // XCD swizzle over flattened 256 blocks, then decode (nt, mt, kz).
    int flat = (blockIdx.z * gridDim.y + blockIdx.y) * gridDim.x + blockIdx.x;
    flat = (flat & 7) * 32 + (flat >> 3);   // bijective on [0,256)
    const int  nt = flat & 3;
    const int  mt = (flat >> 2) & 31;
    const int  kz = flat >> 7;
    const long bm0 = (long)mt * 256;
    const long bn0 = (long)nt * 256;
    const long k0  = (long)kz * KW;

    // staging: row = tid/4 (+128 on call 2), chunk pre-swizzled at source
    const int srow   = tid >> 2;
    const int schunk = (tid & 3) ^ ((tid >> 3) & 3);
    const unsigned short* gA = A + (bm0 + srow) * (long)K + k0 + schunk * 8;
    const unsigned short* gB = B + (bn0 + srow) * (long)K + k0 + schunk * 8;
    char* lbase = (char*)lds;

    unsigned offA[8], offB[4];
    #pragma unroll
    for (int i = 0; i < 8; i++) {
        const unsigned lo = (unsigned)((wm * 128 + i * 16 + m16) * 64 + quad * 16);
        offA[i] = lo ^ (((lo >> 7) & 3) << 4);
    }
    #pragma unroll
    for (int j = 0; j < 4; j++) {
        const unsigned lo = (unsigned)((wn * 64 + j * 16 + m16) * 64 + quad * 16);
        offB[j] = lo ^ (((lo >> 7) & 3) << 4);
    }

    f32x4 acc[8][4];
    #pragma unroll
    for (int i = 0; i < 8; i++)
        #pragma unroll
        for (int j = 0; j < 4; j++)
            acc[i][j] = (f32x4)0.0f;

    const int NT = KW >> 6;   // 32 K-tiles

    #define STG_A(t, kh) do { \
        char* _d = lbase + ((t) & 1) * BUFB + (kh) * AKH + tid * 16; \
        const unsigned short* _s = gA + (long)(t) * 64 + (kh) * 32; \
        load16_to_lds(_s, _d); \
        load16_to_lds(_s + 128l * K, _d + 8192); } while (0)

    #define STG_B(t, kh) do { \
        char* _d = lbase + ((t) & 1) * BUFB + BOFF + (kh) * BKH + tid * 16; \
        const unsigned short* _s = gB + (long)(t) * 64 + (kh) * 32; \
        load16_to_lds(_s, _d); \
        load16_to_lds(_s + 128l * K, _d + 8192); } while (0)

    // prologue: t0 fully (8) + t1 {B.kh0, A.kh0, B.kh1} (6); retire t0.
    STG_B(0, 0); STG_A(0, 0); STG_B(0, 1); STG_A(0, 1);
    STG_B(1, 0); STG_A(1, 0); STG_B(1, 1);
    VMC(KEEP);
    __builtin_amdgcn_s_barrier();

    for (int t = 0; t < NT; ++t) {
        char* bufA = lbase + (t & 1) * BUFB;
        char* bufB = bufA + BOFF;
        bf16x8 af[4], bf[4];

        // ---- phase 1: B.kh0 + A.mh0.kh0 ----
        #pragma unroll
        for (int j = 0; j < 4; j++) bf[j] = *(const bf16x8*)(bufB + offB[j]);
        #pragma unroll
        for (int i = 0; i < 4; i++) af[i] = *(const bf16x8*)(bufA + offA[i]);
        if (t + 1 < NT) STG_A(t + 1, 1);
        __builtin_amdgcn_s_barrier();
        LGKM0_FENCE();
        __builtin_amdgcn_s_setprio(1);
        #pragma unroll
        for (int i = 0; i < 4; i++)
            #pragma unroll
            for (int j = 0; j < 4; j++)
                acc[i][j] = __builtin_amdgcn_mfma_f32_16x16x32_bf16(
                    af[i], bf[j], acc[i][j], 0, 0, 0);
        __builtin_amdgcn_s_setprio(0);
        __builtin_amdgcn_s_barrier();

        // ---- phase 2: A.mh1.kh0 ----
        #pragma unroll
        for (int i = 0; i < 4; i++) af[i] = *(const bf16x8*)(bufA + offA[4 + i]);
        if (t + 2 < NT) STG_B(t + 2, 0);
        __builtin_amdgcn_s_barrier();
        LGKM0_FENCE();
        __builtin_amdgcn_s_setprio(1);
        #pragma unroll
        for (int i = 0; i < 4; i++)
            #pragma unroll
            for (int j = 0; j < 4; j++)
                acc[4 + i][j] = __builtin_amdgcn_mfma_f32_16x16x32_bf16(
                    af[i], bf[j], acc[4 + i][j], 0, 0, 0);
        __builtin_amdgcn_s_setprio(0);
        __builtin_amdgcn_s_barrier();

        // ---- phase 3: B.kh1 + A.mh0.kh1 ----
        #pragma unroll
        for (int j = 0; j < 4; j++) bf[j] = *(const bf16x8*)(bufB + BKH + offB[j]);
        #pragma unroll
        for (int i = 0; i < 4; i++) af[i] = *(const bf16x8*)(bufA + AKH + offA[i]);
        if (t + 2 < NT) STG_A(t + 2, 0);
        __builtin_amdgcn_s_barrier();
        LGKM0_FENCE();
        __builtin_amdgcn_s_setprio(1);
        #pragma unroll
        for (int i = 0; i < 4; i++)
            #pragma unroll
            for (int j = 0; j < 4; j++)
                acc[i][j] = __builtin_amdgcn_mfma_f32_16x16x32_bf16(
                    af[i], bf[j], acc[i][j], 0, 0, 0);
        __builtin_amdgcn_s_setprio(0);
        __builtin_amdgcn_s_barrier();

        // ---- phase 4: A.mh1.kh1 + group-end vmcnt ----
        #pragma unroll
        for (int i = 0; i < 4; i++) af[i] = *(const bf16x8*)(bufA + AKH + offA[4 + i]);
        if (t + 2 < NT) STG_B(t + 2, 1);
        __builtin_amdgcn_s_barrier();
        LGKM0_FENCE();
        __builtin_amdgcn_s_setprio(1);
        #pragma unroll
        for (int i = 0; i < 4; i++)
            #pragma unroll
            for (int j = 0; j < 4; j++)
                acc[4 + i][j] = __builtin_amdgcn_mfma_f32_16x16x32_bf16(
                    af[i], bf[j], acc[4 + i][j], 0, 0, 0);
        __builtin_amdgcn_s_setprio(0);
        if (t + 2 < NT) VMC(KEEP);
        else            VMC(0);
        __builtin_amdgcn_s_barrier();
    }
    #undef STG_A
    #undef STG_B

    // epilogue: fp32 atomicAdd (device-scope default); 2 addends/element.
    const long baseRow = bm0 + wm * 128 + quad * 4;
    const long baseCol = bn0 + wn * 64 + m16;
    #pragma unroll
    for (int i = 0; i < 8; i++) {
        #pragma unroll
        for (int j = 0; j < 4; j++) {
            #pragma unroll
            for (int r = 0; r < 4; r++) {
                const long row = baseRow + i * 16 + r;
                const long col = baseCol + j * 16;
                atomicAdd(&C[row * (long)N + col], acc[i][j][r]);
            }
        }
    }
}

extern "C" void kernel_launch(void* const* d_in, const int* in_sizes, int n_in,
                              void* d_out, int out_size, void* d_ws, size_t ws_size,
                              hipStream_t stream) {
    (void)in_sizes; (void)n_in; (void)ws_size;

    const int T = 8192, DIM = 1024, HID = 4096;

    const float* x     = (const float*)d_in[0];  // [T, DIM]
    const float* W_fc  = (const float*)d_in[1];  // [HID, DIM]
    const float* W_prj = (const float*)d_in[2];  // [DIM, HID]
    float* out = (float*)d_out;                  // [T, DIM]

    char* ws = (char*)d_ws;
    unsigned short* h   = (unsigned short*)ws;                  // 64 MiB [T,HID]
    unsigned short* xb  = (unsigned short*)(ws + (64l << 20));  // 16 MiB
    unsigned short* wfb = (unsigned short*)(ws + (80l << 20));  //  8 MiB
    unsigned short* wpb = (unsigned short*)(ws + (88l << 20));  //  8 MiB

    // zero out (split-K atomic target); capture-legal memset node
    hipMemsetAsync(out, 0, (size_t)out_size, stream);

    // prepass: all three fp32 -> bf16 in ONE launch
    cvt_all<<<4096, 256, 0, stream>>>(
        (const float4*)x,     (ushort4*)xb,
        (const float4*)W_fc,  (ushort4*)wfb,
        (const float4*)W_prj, (ushort4*)wpb);

    // GEMM1: h = relu(x . W_fc^T)^2  [8192,4096] bf16, 128x256, 2 blocks/CU
    gemm_h1<<<dim3(HID / 256, T / 128), dim3(512), 0, stream>>>(
        xb, wfb, h, T, HID, DIM);

    // GEMM2: out += h . W_proj^T     [8192,1024] fp32, 256x256 split-K=2
    gemm2_sk8<<<dim3(DIM / 256, T / 256, 2), dim3(512), 0, stream>>>(
        h, wpb, out, T, DIM, HID);
}

// Round 8
// 256.181 us; speedup vs baseline: 1.1088x; 1.1088x over previous
//
#include <hip/hip_runtime.h>
#include <stdint.h>

// ============================================================================
// ExpertMLP: out = relu(x @ W_fc^T)^2 @ W_proj^T    (fp32 in/out, bf16 MFMA)
// R14: revert R13 (split-K + atomics regressed: +25 us, no per-tile gain).
//   GEMM1 = gemm_h1 (R12, best measured 82.1 us) unchanged.
//   GEMM2 = gemm_p2: faithful m97 structure — 128x128 tile, BK=64, 256 thr /
//     4 waves (wave 64x64), SINGLE 32 KiB LDS buffer, plain __syncthreads,
//     NO manual waitcnt (compiler-placed), __launch_bounds__(256,3) =>
//     3 blocks/CU = 12 waves/CU. Mechanism: implicit cross-block overlap
//     (m114) hides the staging drain — the one lever all prior GEMM2
//     variants (1-2 blocks/CU) lacked. XOR bank swizzle retained
//     (read-side swizzle + pre-swizzled gload_lds source).
//   cvt_all unchanged. No memset, no atomics.
// ws: h[64Mi] | x_bf[16Mi] | wfc_bf[8Mi] | wproj_bf[8Mi] = 96 MiB.
// ============================================================================

typedef __attribute__((ext_vector_type(8))) short bf16x8;   // 8 bf16 = 4 VGPRs
typedef __attribute__((ext_vector_type(4))) float f32x4;    // MFMA C/D

typedef const __attribute__((address_space(1))) unsigned int* gas_u32p;
typedef __attribute__((address_space(3))) unsigned int* las_u32p;

__device__ __forceinline__ void load16_to_lds(const void* gptr, void* lptr) {
    __builtin_amdgcn_global_load_lds((gas_u32p)gptr, (las_u32p)lptr, 16, 0, 0);
}

__device__ __forceinline__ void dsr128(bf16x8& d, unsigned off) {
    asm volatile("ds_read_b128 %0, %1" : "=v"(d) : "v"(off));
}

__device__ __forceinline__ unsigned short f2bf(float f) {
    unsigned int u = __float_as_uint(f);
    u += 0x7FFFu + ((u >> 16) & 1u);   // RNE; finite inputs
    return (unsigned short)(u >> 16);
}

#define LGKM(n) do { \
    asm volatile("s_waitcnt lgkmcnt(%0)" :: "i"(n) : "memory"); \
    __builtin_amdgcn_sched_barrier(0); } while (0)
#define VMC(n) do { \
    asm volatile("s_waitcnt vmcnt(%0)" :: "i"(n) : "memory"); \
    __builtin_amdgcn_sched_barrier(0); } while (0)

// --------------------------------------------------------------------------
// Single fused fp32->bf16 prepass: x (2M float4) | W_fc (1M) | W_proj (1M).
// --------------------------------------------------------------------------
__global__ void cvt_all(const float4* __restrict__ x,  ushort4* __restrict__ xb,
                        const float4* __restrict__ wf, ushort4* __restrict__ wfb,
                        const float4* __restrict__ wp, ushort4* __restrict__ wpb)
{
    const int base = blockIdx.x * 1024 + threadIdx.x;
    #pragma unroll
    for (int j = 0; j < 4; j++) {
        const int i = base + j * 256;
        const float4* s; ushort4* d; int k;
        if (i < (1 << 21))            { s = x;  d = xb;  k = i; }
        else if (i < 3 * (1 << 20))   { s = wf; d = wfb; k = i - (1 << 21); }
        else                          { s = wp; d = wpb; k = i - 3 * (1 << 20); }
        float4 v = s[k];
        ushort4 o;
        o.x = f2bf(v.x); o.y = f2bf(v.y); o.z = f2bf(v.z); o.w = f2bf(v.w);
        d[k] = o;
    }
}

// --------------------------------------------------------------------------
// GEMM1: h = relu(A.B^T)^2, bf16 out. BM=128 BN=256 BK=32. (R12, verified)
// 512 thr, 8 waves 2Mx4N (wave 64x64). LDS: 3 bufs x 24KiB -> 2 blocks/CU.
// --------------------------------------------------------------------------
__global__ __launch_bounds__(512, 4)
void gemm_h1(const unsigned short* __restrict__ A,
             const unsigned short* __restrict__ B,
             unsigned short* __restrict__ C, int M, int N, int K)
{
    constexpr int ABYT = 8192;              // A region: 128r x 32k x 2B
    constexpr int BBYT = 16384;             // B region: 256r x 32k x 2B
    constexpr int BUFB = ABYT + BBYT;       // 24 KiB
    (void)M;

    __shared__ char lds[3 * BUFB];          // 72 KiB -> 2 blocks/CU

    const int tid  = threadIdx.x;
    const int lane = tid & 63;
    const int wave = tid >> 6;
    const int wm   = wave >> 2;             // 0..1 -> rows wm*64
    const int wn   = wave & 3;              // 0..3 -> cols wn*64
    const int quad = lane >> 4;
    const int m16  = lane & 15;

    const int gx = gridDim.x;               // 16
    int flat = blockIdx.y * gx + blockIdx.x;
    const int cpx = (gx * gridDim.y) >> 3;  // 128
    flat = (flat & 7) * cpx + (flat >> 3);
    const long bm0 = (long)(flat & 63) * 128;
    const long bn0 = (long)(flat >> 6) * 256;

    const int srow   = tid >> 2;
    const int schunk = (tid & 3) ^ ((tid >> 3) & 3);
    const unsigned short* gA = A + (bm0 + srow) * (long)K + schunk * 8;
    const unsigned short* gB = B + (bn0 + srow) * (long)K + schunk * 8;

    unsigned offA[4], offB[4];
    #pragma unroll
    for (int i = 0; i < 4; i++) {
        const unsigned lo = (unsigned)((wm * 64 + i * 16 + m16) * 64 + quad * 16);
        offA[i] = lo ^ (((lo >> 7) & 3) << 4);
    }
    #pragma unroll
    for (int j = 0; j < 4; j++) {
        const unsigned lo = (unsigned)((wn * 64 + j * 16 + m16) * 64 + quad * 16);
        offB[j] = ABYT + (lo ^ (((lo >> 7) & 3) << 4));
    }

    const unsigned base =
        (unsigned)(unsigned long long)(las_u32p)(void*)lds;

    f32x4 acc[4][4];
    #pragma unroll
    for (int i = 0; i < 4; i++)
        #pragma unroll
        for (int j = 0; j < 4; j++)
            acc[i][j] = (f32x4)0.0f;

    const int NT = K >> 5;   // BK=32 -> 32 tiles at K=1024

    #define STG(po_, t_) do { \
        char* _d = (char*)lds + (po_) + tid * 16; \
        load16_to_lds(gA + (long)(t_) * 32, _d); \
        const unsigned short* _sB = gB + (long)(t_) * 32; \
        load16_to_lds(_sB, _d + ABYT); \
        load16_to_lds(_sB + 128l * K, _d + ABYT + 8192); } while (0)

    STG(0, 0);
    if (NT > 1) {
        STG(BUFB, 1);
        VMC(3);
    } else {
        VMC(0);
    }
    __builtin_amdgcn_s_barrier();

    unsigned co = 0, no = BUFB, po = 2 * BUFB;

    for (int t = 0; t < NT; ++t) {
        bf16x8 a[4], b[4];

        #pragma unroll
        for (int j = 0; j < 4; j++) dsr128(b[j], base + co + offB[j]);
        #pragma unroll
        for (int i = 0; i < 4; i++) dsr128(a[i], base + co + offA[i]);

        if (t + 2 < NT) STG(po, t + 2);

        LGKM(2);
        __builtin_amdgcn_s_setprio(1);
        #pragma unroll
        for (int i = 0; i < 2; i++)
            #pragma unroll
            for (int j = 0; j < 4; j++)
                acc[i][j] = __builtin_amdgcn_mfma_f32_16x16x32_bf16(
                    a[i], b[j], acc[i][j], 0, 0, 0);
        __builtin_amdgcn_s_setprio(0);

        LGKM(0);
        __builtin_amdgcn_s_setprio(1);
        #pragma unroll
        for (int i = 2; i < 4; i++)
            #pragma unroll
            for (int j = 0; j < 4; j++)
                acc[i][j] = __builtin_amdgcn_mfma_f32_16x16x32_bf16(
                    a[i], b[j], acc[i][j], 0, 0, 0);
        __builtin_amdgcn_s_setprio(0);

        if (t + 2 < NT) VMC(3);
        else            VMC(0);
        __builtin_amdgcn_s_barrier();

        const unsigned tmp = po; po = co; co = no; no = tmp;
    }
    #undef STG

    const long baseRow = bm0 + wm * 64 + quad * 4;
    const long baseCol = bn0 + wn * 64 + m16;
    #pragma unroll
    for (int i = 0; i < 4; i++) {
        #pragma unroll
        for (int j = 0; j < 4; j++) {
            #pragma unroll
            for (int r = 0; r < 4; r++) {
                float v = acc[i][j][r];
                v = (v > 0.0f) ? v * v : 0.0f;
                const long row = baseRow + i * 16 + r;
                const long col = baseCol + j * 16;
                C[row * (long)N + col] = f2bf(v);
            }
        }
    }
}

// --------------------------------------------------------------------------
// GEMM2: C[M,N] = A[M,K].B[N,K]^T fp32 out — m97 structure.
// 128x128 tile, BK=64, 256 thr / 4 waves (2Mx2N, wave 64x64).
// SINGLE LDS buffer (sA 16K + sB 16K = 32 KiB), plain __syncthreads,
// compiler-placed waitcnts, 3 blocks/CU (12 waves/CU) for implicit
// cross-block overlap of the staging drain (m97/m114 mechanism).
// LDS row = 128 B (64 k x 2B); XOR swizzle: byte-col ^ ((row&7)<<4),
// applied on the read side and pre-applied to the gload_lds SOURCE chunk.
// --------------------------------------------------------------------------
__global__ __launch_bounds__(256, 3)
void gemm_p2(const unsigned short* __restrict__ A,
             const unsigned short* __restrict__ B,
             float* __restrict__ C, int M, int N, int K)
{
    __shared__ unsigned short sA[128 * 64];   // 16 KiB
    __shared__ unsigned short sB[128 * 64];   // 16 KiB
    (void)M;

    const int tid  = threadIdx.x;
    const int lane = tid & 63;
    const int wave = tid >> 6;             // 0..3
    const int wm   = wave >> 1;            // 0..1 -> rows wm*64
    const int wn   = wave & 1;             // 0..1 -> cols wn*64
    const int quad = lane >> 4;
    const int m16  = lane & 15;

    // XCD swizzle (grid 8x64 = 512 blocks, %8==0, bijective)
    const int gx = gridDim.x;              // 8
    int flat = blockIdx.y * gx + blockIdx.x;
    const int cpx = (gx * gridDim.y) >> 3; // 64
    flat = (flat & 7) * cpx + (flat >> 3);
    const long bm0 = (long)(flat / gx) * 128;
    const long bn0 = (long)(flat % gx) * 128;

    // staging: 4 calls/operand; call c covers rows c*32..c*32+31.
    // thread -> (row = tid/8, chunk = tid&7); source chunk pre-swizzled so
    // linear LDS dest + swizzled read agree: j = ch ^ (row&7).
    const int srow   = tid >> 3;                       // 0..31
    const int schunk = (tid & 7) ^ ((tid >> 3) & 7);
    const unsigned short* gA = A + (bm0 + srow) * (long)K + schunk * 8;
    const unsigned short* gB = B + (bn0 + srow) * (long)K + schunk * 8;

    f32x4 acc[4][4];
    #pragma unroll
    for (int i = 0; i < 4; i++)
        #pragma unroll
        for (int j = 0; j < 4; j++)
            acc[i][j] = (f32x4)0.0f;

    const int NT = K >> 6;   // 64 tiles at K=4096

    #define STGP(t_) do { \
        _Pragma("unroll") \
        for (int c = 0; c < 4; c++) \
            load16_to_lds(gA + (long)(c * 32) * K + (long)(t_) * 64, \
                          (char*)sA + c * 4096 + tid * 16); \
        _Pragma("unroll") \
        for (int c = 0; c < 4; c++) \
            load16_to_lds(gB + (long)(c * 32) * K + (long)(t_) * 64, \
                          (char*)sB + c * 4096 + tid * 16); } while (0)

    STGP(0);

    const int rswz = (m16 & 7) << 4;       // row&7 == m16&7 for all frags

    for (int t = 0; t < NT; ++t) {
        __syncthreads();                   // compiler drains vmcnt -> data ready

        #pragma unroll
        for (int kh = 0; kh < 2; kh++) {
            const int col = (kh * 64 + quad * 16) ^ rswz;
            bf16x8 a[4], b[4];
            #pragma unroll
            for (int i = 0; i < 4; i++)
                a[i] = *(const bf16x8*)((const char*)sA
                        + (wm * 64 + i * 16 + m16) * 128 + col);
            #pragma unroll
            for (int j = 0; j < 4; j++)
                b[j] = *(const bf16x8*)((const char*)sB
                        + (wn * 64 + j * 16 + m16) * 128 + col);
            #pragma unroll
            for (int i = 0; i < 4; i++)
                #pragma unroll
                for (int j = 0; j < 4; j++)
                    acc[i][j] = __builtin_amdgcn_mfma_f32_16x16x32_bf16(
                        a[i], b[j], acc[i][j], 0, 0, 0);
        }

        __syncthreads();                   // all reads done before overwrite
        if (t + 1 < NT) STGP(t + 1);
    }
    #undef STGP

    // epilogue: C/D layout col=lane&15, row=quad*4+reg
    const long baseRow = bm0 + wm * 64 + quad * 4;
    const long baseCol = bn0 + wn * 64 + m16;
    #pragma unroll
    for (int i = 0; i < 4; i++) {
        #pragma unroll
        for (int j = 0; j < 4; j++) {
            #pragma unroll
            for (int r = 0; r < 4; r++) {
                const long row = baseRow + i * 16 + r;
                const long col = baseCol + j * 16;
                C[row * (long)N + col] = acc[i][j][r];
            }
        }
    }
}

extern "C" void kernel_launch(void* const* d_in, const int* in_sizes, int n_in,
                              void* d_out, int out_size, void* d_ws, size_t ws_size,
                              hipStream_t stream) {
    (void)in_sizes; (void)n_in; (void)out_size; (void)ws_size;

    const int T = 8192, DIM = 1024, HID = 4096;

    const float* x     = (const float*)d_in[0];  // [T, DIM]
    const float* W_fc  = (const float*)d_in[1];  // [HID, DIM]
    const float* W_prj = (const float*)d_in[2];  // [DIM, HID]
    float* out = (float*)d_out;                  // [T, DIM]

    char* ws = (char*)d_ws;
    unsigned short* h   = (unsigned short*)ws;                  // 64 MiB [T,HID]
    unsigned short* xb  = (unsigned short*)(ws + (64l << 20));  // 16 MiB
    unsigned short* wfb = (unsigned short*)(ws + (80l << 20));  //  8 MiB
    unsigned short* wpb = (unsigned short*)(ws + (88l << 20));  //  8 MiB

    // prepass: all three fp32 -> bf16 in ONE launch
    cvt_all<<<4096, 256, 0, stream>>>(
        (const float4*)x,     (ushort4*)xb,
        (const float4*)W_fc,  (ushort4*)wfb,
        (const float4*)W_prj, (ushort4*)wpb);

    // GEMM1: h = relu(x . W_fc^T)^2  [8192,4096] bf16, 128x256, 2 blocks/CU
    gemm_h1<<<dim3(HID / 256, T / 128), dim3(512), 0, stream>>>(
        xb, wfb, h, T, HID, DIM);

    // GEMM2: out = h . W_proj^T      [8192,1024] fp32, m97 128x128, 3 blk/CU
    gemm_p2<<<dim3(DIM / 128, T / 128), dim3(256), 0, stream>>>(
        h, wpb, out, T, DIM, HID);
}